// Round 16
// baseline (814.229 us; speedup 1.0000x reference)
//
#include <hip/hip_runtime.h>
#include <hip/hip_bf16.h>

// PCT segmentation forward. R16 = resubmit of R15 (prior bench died in harness
// infra, no kernel diagnostics). R15 = R13 (780us best) + two isolated fixes:
// - attn_pv: stageV issued AFTER the Kq-drain barrier -> Vv latency hidden
//   behind QK+exp compute (R14's idea minus the harmful Kq dbuf).
// - rs_k: plain partial stores rsp[8][B][N]; zero_k + atomics deleted.
// Trunk: R13 routing (ntB BK=128 for K%128==0 calls; K1 for conv2/cf/s1).

#define NPTS 4096
#define BATCH 2
#define MSPLIT 4
#define RSSPLIT 8
static constexpr float INV_STD = 0.9999950000374997f;  // 1/sqrt(1+1e-5)

__device__ __forceinline__ float bf2f(unsigned short u) {
    return __uint_as_float(((unsigned int)u) << 16);
}
__device__ __forceinline__ unsigned short f2bf(float f) {
    unsigned int x = __float_as_uint(f);
    unsigned int r = (x + 0x7FFFu + ((x >> 16) & 1u)) >> 16;
    return (unsigned short)r;
}

// async global->LDS 16B DMA: LDS base wave-uniform; HW writes lptr+lane*16.
__device__ __forceinline__ void async16(const unsigned short* g, unsigned short* l)
{
    __builtin_amdgcn_global_load_lds(
        (const __attribute__((address_space(1))) unsigned int*)(const void*)g,
        (__attribute__((address_space(3))) unsigned int*)(void*)l,
        16, 0, 0);
}

typedef __attribute__((ext_vector_type(8))) short short8;
typedef __attribute__((ext_vector_type(4))) float f32x4;

// ---------------- weight pre-split ----------------
struct WSplit {
    const float* src[14];
    int n[14];
    long long off[14];   // ushort offset of hi plane; lo at off+n
};

__global__ __launch_bounds__(256)
void presplit_k(WSplit d, unsigned short* __restrict__ wbuf)
{
    int wi = blockIdx.y;
    int i = blockIdx.x * 256 + threadIdx.x;
    int n = d.n[wi];
    if (i >= n) return;
    float v = d.src[wi][i];
    unsigned short h = f2bf(v);
    unsigned short* dst = wbuf + d.off[wi];
    dst[i] = h;
    dst[n + i] = f2bf(v - bf2f(h));
}

// shared epilogue
__device__ __forceinline__ void nt_epilogue(
    float y, int rg, int cg, int b, int Nb,
    const float* bias, int bias_mode,
    const float* bng, const float* bnb,
    const unsigned short* res, long long res_bs, int res_ld, long long res_po,
    int act, int out_mode,
    void* Cp, long long c_bs, int c_ld, long long c_po)
{
    if (bias) {
        if (bias_mode == 3)      y += bias[rg];
        else if (bias_mode == 2) y += bias[b * Nb + cg];
        else                     y += bias[cg];
    }
    if (bng) y = y * (INV_STD * bng[cg]) + bnb[cg];
    if (act == 1) y = fmaxf(y, 0.f);
    else if (act == 2) y = (y > 0.f) ? y : 0.2f * y;
    if (res) {
        long long ri_ = (long long)b * res_bs + (long long)rg * res_ld + cg;
        y += bf2f(res[ri_]) + bf2f(res[res_po + ri_]);
    }
    long long ci = (long long)b * c_bs + (long long)rg * c_ld + cg;
    if (out_mode == 0) {
        unsigned short* C = (unsigned short*)Cp;
        unsigned short h = f2bf(y);
        C[ci] = h;
        C[c_po + ci] = f2bf(y - bf2f(h));
    } else if (out_mode == 1) {
        ((unsigned short*)Cp)[ci] = f2bf(y);
    } else {
        if (cg < Nb) ((float*)Cp)[ci] = y;
    }
}

// ---------------- K1: split-bf16 NT GEMM, 64x64 tile, BK=64 ----------------
__global__ __launch_bounds__(256)
void gemm_nt_split(const unsigned short* __restrict__ A, long long a_bs, int a_lda, long long a_po,
                   const unsigned short* __restrict__ B, long long b_bs, int b_lda, long long b_po,
                   void* __restrict__ Cp, long long c_bs, int c_ld, long long c_po,
                   int Nb, int K,
                   const float* __restrict__ bias, int bias_mode,
                   const float* __restrict__ bng, const float* __restrict__ bnb,
                   const unsigned short* __restrict__ res, long long res_bs, int res_ld, long long res_po,
                   int act, int out_mode)
{
    __shared__ unsigned short As[2][64 * 64];
    __shared__ unsigned short Bs[2][64 * 64];
    const int b = blockIdx.z;
    const int m0 = blockIdx.y * 64, n0 = blockIdx.x * 64;
    const int t = threadIdx.x;
    const int lane = t & 63, w = t >> 6;
    const int wr = (w >> 1) * 32, wc = (w & 1) * 32;
    const int ml = lane & 15, q = lane >> 4;

    f32x4 acc[2][2] = {};

    for (int k0 = 0; k0 < K; k0 += 64) {
        __syncthreads();
        #pragma unroll
        for (int e = 0; e < 2; e++) {
            int idx = t + e * 256;
            int row = idx >> 3, blk = idx & 7;
            int gblk = blk ^ (row & 7);
            int lofs = (e * 256 + (t & 192)) * 8;
            const unsigned short* sA = A + (long long)b * a_bs
                                     + (long long)(m0 + row) * a_lda + k0 + gblk * 8;
            const unsigned short* sB = B + (long long)b * b_bs
                                     + (long long)(n0 + row) * b_lda + k0 + gblk * 8;
            async16(sA,        &As[0][0] + lofs);
            async16(sA + a_po, &As[1][0] + lofs);
            async16(sB,        &Bs[0][0] + lofs);
            async16(sB + b_po, &Bs[1][0] + lofs);
        }
        __syncthreads();
        #pragma unroll
        for (int kk = 0; kk < 2; kk++) {
            short8 ah[2], al[2], bh[2], bl[2];
            #pragma unroll
            for (int it = 0; it < 2; it++) {
                int row = wr + it * 16 + ml;
                int slot = (kk * 4 + q) ^ (row & 7);
                ah[it] = *(const short8*)(&As[0][row * 64 + slot * 8]);
                al[it] = *(const short8*)(&As[1][row * 64 + slot * 8]);
            }
            #pragma unroll
            for (int jt = 0; jt < 2; jt++) {
                int row = wc + jt * 16 + ml;
                int slot = (kk * 4 + q) ^ (row & 7);
                bh[jt] = *(const short8*)(&Bs[0][row * 64 + slot * 8]);
                bl[jt] = *(const short8*)(&Bs[1][row * 64 + slot * 8]);
            }
            #pragma unroll
            for (int it = 0; it < 2; it++)
                #pragma unroll
                for (int jt = 0; jt < 2; jt++) {
                    acc[it][jt] = __builtin_amdgcn_mfma_f32_16x16x32_bf16(ah[it], bh[jt], acc[it][jt], 0, 0, 0);
                    acc[it][jt] = __builtin_amdgcn_mfma_f32_16x16x32_bf16(ah[it], bl[jt], acc[it][jt], 0, 0, 0);
                    acc[it][jt] = __builtin_amdgcn_mfma_f32_16x16x32_bf16(al[it], bh[jt], acc[it][jt], 0, 0, 0);
                }
        }
    }

    #pragma unroll
    for (int it = 0; it < 2; it++)
        #pragma unroll
        for (int jt = 0; jt < 2; jt++)
            #pragma unroll
            for (int r = 0; r < 4; r++)
                nt_epilogue(acc[it][jt][r], m0 + wr + it * 16 + q * 4 + r,
                            n0 + wc + jt * 16 + ml, b, Nb,
                            bias, bias_mode, bng, bnb, res, res_bs, res_ld, res_po,
                            act, out_mode, Cp, c_bs, c_ld, c_po);
}

// ---------------- K1B: split-bf16 NT GEMM, 64x64 tile, BK=128 ----------------
__global__ __launch_bounds__(256)
void gemm_nt_splitB(const unsigned short* __restrict__ A, long long a_bs, int a_lda, long long a_po,
                    const unsigned short* __restrict__ B, long long b_bs, int b_lda, long long b_po,
                    void* __restrict__ Cp, long long c_bs, int c_ld, long long c_po,
                    int Nb, int K,
                    const float* __restrict__ bias, int bias_mode,
                    const float* __restrict__ bng, const float* __restrict__ bnb,
                    const unsigned short* __restrict__ res, long long res_bs, int res_ld, long long res_po,
                    int act, int out_mode)
{
    __shared__ unsigned short As[2][2][64 * 64];   // [plane][sub] 32 KB
    __shared__ unsigned short Bs[2][2][64 * 64];   // 32 KB
    const int b = blockIdx.z;
    const int m0 = blockIdx.y * 64, n0 = blockIdx.x * 64;
    const int t = threadIdx.x;
    const int lane = t & 63, w = t >> 6;
    const int wr = (w >> 1) * 32, wc = (w & 1) * 32;
    const int ml = lane & 15, q = lane >> 4;

    f32x4 acc[2][2] = {};

    for (int k0 = 0; k0 < K; k0 += 128) {
        __syncthreads();
        #pragma unroll
        for (int sub = 0; sub < 2; sub++) {
            int kb = k0 + sub * 64;
            #pragma unroll
            for (int e = 0; e < 2; e++) {
                int idx = t + e * 256;
                int row = idx >> 3, blk = idx & 7;
                int gblk = blk ^ (row & 7);
                int lofs = (e * 256 + (t & 192)) * 8;
                const unsigned short* sA = A + (long long)b * a_bs
                                         + (long long)(m0 + row) * a_lda + kb + gblk * 8;
                const unsigned short* sB = B + (long long)b * b_bs
                                         + (long long)(n0 + row) * b_lda + kb + gblk * 8;
                async16(sA,        &As[0][sub][0] + lofs);
                async16(sA + a_po, &As[1][sub][0] + lofs);
                async16(sB,        &Bs[0][sub][0] + lofs);
                async16(sB + b_po, &Bs[1][sub][0] + lofs);
            }
        }
        __syncthreads();
        #pragma unroll
        for (int sub = 0; sub < 2; sub++)
            #pragma unroll
            for (int kk = 0; kk < 2; kk++) {
                short8 ah[2], al[2], bh[2], bl[2];
                #pragma unroll
                for (int it = 0; it < 2; it++) {
                    int row = wr + it * 16 + ml;
                    int slot = (kk * 4 + q) ^ (row & 7);
                    ah[it] = *(const short8*)(&As[0][sub][row * 64 + slot * 8]);
                    al[it] = *(const short8*)(&As[1][sub][row * 64 + slot * 8]);
                }
                #pragma unroll
                for (int jt = 0; jt < 2; jt++) {
                    int row = wc + jt * 16 + ml;
                    int slot = (kk * 4 + q) ^ (row & 7);
                    bh[jt] = *(const short8*)(&Bs[0][sub][row * 64 + slot * 8]);
                    bl[jt] = *(const short8*)(&Bs[1][sub][row * 64 + slot * 8]);
                }
                #pragma unroll
                for (int it = 0; it < 2; it++)
                    #pragma unroll
                    for (int jt = 0; jt < 2; jt++) {
                        acc[it][jt] = __builtin_amdgcn_mfma_f32_16x16x32_bf16(ah[it], bh[jt], acc[it][jt], 0, 0, 0);
                        acc[it][jt] = __builtin_amdgcn_mfma_f32_16x16x32_bf16(ah[it], bl[jt], acc[it][jt], 0, 0, 0);
                        acc[it][jt] = __builtin_amdgcn_mfma_f32_16x16x32_bf16(al[it], bh[jt], acc[it][jt], 0, 0, 0);
                    }
            }
    }

    #pragma unroll
    for (int it = 0; it < 2; it++)
        #pragma unroll
        for (int jt = 0; jt < 2; jt++)
            #pragma unroll
            for (int r = 0; r < 4; r++)
                nt_epilogue(acc[it][jt][r], m0 + wr + it * 16 + q * 4 + r,
                            n0 + wc + jt * 16 + ml, b, Nb,
                            bias, bias_mode, bng, bnb, res, res_bs, res_ld, res_po,
                            act, out_mode, Cp, c_bs, c_ld, c_po);
}

// ---------------- E1: rsp[ms][b][p] = partial sum_m exp(e[p][m]) ----------------
__global__ __launch_bounds__(256)
void rs_k(const unsigned short* __restrict__ xq, float* __restrict__ rsp)
{
    __shared__ unsigned short Kq[2][64 * 64];
    const int b = blockIdx.z;
    const int p0 = blockIdx.y * 64;
    const int ms = blockIdx.x;
    const int m_beg = ms * (NPTS / RSSPLIT);
    const unsigned short* xqB = xq + (long long)b * NPTS * 128;
    const int t = threadIdx.x;
    const int lane = t & 63, w = t >> 6;
    const int pw = w * 16;
    const int ml = lane & 15, q = lane >> 4;

    short8 af[4];
    #pragma unroll
    for (int ks = 0; ks < 4; ks++)
        af[ks] = *(const short8*)(xqB + (long long)(p0 + pw + ml) * 128 + ks * 32 + q * 8);

    float rsum[4] = {0.f, 0.f, 0.f, 0.f};

    for (int m0 = m_beg; m0 < m_beg + NPTS / RSSPLIT; m0 += 64) {
        __syncthreads();
        #pragma unroll
        for (int e = 0; e < 4; e++) {
            int idx = t + e * 256;
            int sub = idx >> 9, row = (idx >> 3) & 63, blk = idx & 7;
            int gblk = blk ^ (row & 7);
            int lofs = (e * 256 + (t & 192)) * 8;
            async16(xqB + (long long)(m0 + row) * 128 + sub * 64 + gblk * 8,
                    &Kq[0][0] + lofs);
        }
        __syncthreads();
        f32x4 acc[4] = {};
        #pragma unroll
        for (int ks = 0; ks < 4; ks++) {
            int kh = ks >> 1, kk = ks & 1;
            #pragma unroll
            for (int jt = 0; jt < 4; jt++) {
                int row = jt * 16 + ml;
                int slot = (kk * 4 + q) ^ (row & 7);
                short8 bf = *(const short8*)(&Kq[kh][row * 64 + slot * 8]);
                acc[jt] = __builtin_amdgcn_mfma_f32_16x16x32_bf16(af[ks], bf, acc[jt], 0, 0, 0);
            }
        }
        #pragma unroll
        for (int jt = 0; jt < 4; jt++)
            #pragma unroll
            for (int r = 0; r < 4; r++)
                rsum[r] += __expf(acc[jt][r]);
    }
    #pragma unroll
    for (int r = 0; r < 4; r++) {
        float s = rsum[r];
        s += __shfl_xor(s, 1); s += __shfl_xor(s, 2);
        s += __shfl_xor(s, 4); s += __shfl_xor(s, 8);
        if (ml == 0)
            rsp[(long long)ms * (BATCH * NPTS) + b * NPTS + p0 + pw + q * 4 + r] = s;
    }
}

// ---------------- E2: QK -> exp/rs[m] -> PV partials + cs partials ----------------
// Vv staged AFTER the Kq-drain barrier: its latency hides behind QK+exp.
__global__ __launch_bounds__(256)
void attn_pv(const unsigned short* __restrict__ xq,   // [B][N][128]
             const unsigned short* __restrict__ xv,   // [B][256][N]
             const float* __restrict__ rsp,           // [RSSPLIT][B][N]
             float* __restrict__ part,                // [B*MSPLIT][N][256]
             float* __restrict__ csp)                 // [B*MSPLIT][N]
{
    __shared__ unsigned short Kq[2][64 * 64];   // 16 KB
    __shared__ unsigned short Vv[256 * 64];     // 32 KB
    __shared__ unsigned short Pl[64][72];       // 9.2 KB
    const int z = blockIdx.z, b = z / MSPLIT, ms = z % MSPLIT;
    const int p0 = blockIdx.y * 64;
    const unsigned short* xqB = xq + (long long)b * NPTS * 128;
    const unsigned short* xvB = xv + (long long)b * 256 * NPTS;
    const int t = threadIdx.x;
    const int lane = t & 63, w = t >> 6;
    const int pw = w * 16;                      // QK p-strip
    const int cw = w * 64;                      // PV c-strip
    const int ml = lane & 15, q = lane >> 4;

    short8 af[4];
    #pragma unroll
    for (int ks = 0; ks < 4; ks++)
        af[ks] = *(const short8*)(xqB + (long long)(p0 + pw + ml) * 128 + ks * 32 + q * 8);

    f32x4 pv[4][4] = {};                        // [p-tile][c-tile]
    float csr[4] = {0.f, 0.f, 0.f, 0.f};

    const int m_beg = ms * (NPTS / MSPLIT);
    for (int m0 = m_beg; m0 < m_beg + NPTS / MSPLIT; m0 += 64) {
        __syncthreads();                        // prior PV done reading Vv
        #pragma unroll
        for (int e = 0; e < 4; e++) {
            int idx = t + e * 256;
            int sub = idx >> 9, row = (idx >> 3) & 63, blk = idx & 7;
            int gblk = blk ^ (row & 7);
            int lofs = (e * 256 + (t & 192)) * 8;
            async16(xqB + (long long)(m0 + row) * 128 + sub * 64 + gblk * 8,
                    &Kq[0][0] + lofs);
        }
        __syncthreads();                        // drains Kq (Vv not yet issued)
        // Vv staged NOW: its drain is the next barrier, after QK+exp compute
        #pragma unroll
        for (int e = 0; e < 8; e++) {
            int idx = t + e * 256;
            int row = idx >> 3, blk = idx & 7;
            int gblk = blk ^ (row & 7);
            int lofs = (e * 256 + (t & 192)) * 8;
            async16(xvB + (long long)row * NPTS + m0 + gblk * 8, Vv + lofs);
        }
        // QK: e[p64][m64] (identical chain to rs_k)
        f32x4 acc[4] = {};
        #pragma unroll
        for (int ks = 0; ks < 4; ks++) {
            int kh = ks >> 1, kk = ks & 1;
            #pragma unroll
            for (int jt = 0; jt < 4; jt++) {
                int row = jt * 16 + ml;
                int slot = (kk * 4 + q) ^ (row & 7);
                short8 bf = *(const short8*)(&Kq[kh][row * 64 + slot * 8]);
                acc[jt] = __builtin_amdgcn_mfma_f32_16x16x32_bf16(af[ks], bf, acc[jt], 0, 0, 0);
            }
        }
        // P' = exp(e)/rs[m], rs = sum of 8 plain partials
        #pragma unroll
        for (int jt = 0; jt < 4; jt++) {
            int m = m0 + jt * 16 + ml;
            float tot = 0.f;
            #pragma unroll
            for (int s = 0; s < RSSPLIT; s++)
                tot += rsp[(long long)s * (BATCH * NPTS) + b * NPTS + m];
            float rvm = 1.f / tot;
            #pragma unroll
            for (int r = 0; r < 4; r++) {
                float pvv = __expf(acc[jt][r]) * rvm;
                csr[r] += pvv;
                Pl[pw + q * 4 + r][jt * 16 + ml] = f2bf(pvv);
            }
        }
        __syncthreads();                        // drains Vv; Pl visible
        // PV: this wave c-strip cw
        #pragma unroll
        for (int kk = 0; kk < 2; kk++) {
            short8 ap[4];
            #pragma unroll
            for (int pst = 0; pst < 4; pst++)
                ap[pst] = *(const short8*)(&Pl[pst * 16 + ml][kk * 32 + q * 8]);
            #pragma unroll
            for (int jt = 0; jt < 4; jt++) {
                int row = cw + jt * 16 + ml;
                int slot = (kk * 4 + q) ^ (row & 7);
                short8 bv = *(const short8*)(&Vv[row * 64 + slot * 8]);
                #pragma unroll
                for (int pst = 0; pst < 4; pst++)
                    pv[pst][jt] = __builtin_amdgcn_mfma_f32_16x16x32_bf16(
                        ap[pst], bv, pv[pst][jt], 0, 0, 0);
            }
        }
    }
    // cs partial: reduce over 16 m-lanes, one PLAIN store per (z, p-row)
    #pragma unroll
    for (int r = 0; r < 4; r++) {
        float s = csr[r];
        s += __shfl_xor(s, 1); s += __shfl_xor(s, 2);
        s += __shfl_xor(s, 4); s += __shfl_xor(s, 8);
        if (ml == 0) csp[(long long)z * NPTS + p0 + pw + q * 4 + r] = s;
    }
    // store PV partials (plain f32)
    float* C = part + (long long)z * ((long long)NPTS * 256);
    #pragma unroll
    for (int pst = 0; pst < 4; pst++)
        #pragma unroll
        for (int jt = 0; jt < 4; jt++)
            #pragma unroll
            for (int r = 0; r < 4; r++) {
                int rg = p0 + pst * 16 + q * 4 + r;
                int cg = cw + jt * 16 + ml;
                C[(long long)rg * 256 + cg] = pv[pst][jt][r];
            }
}

// ---------------- small kernels ----------------
__global__ __launch_bounds__(256)
void conv1_k(const float* __restrict__ x, const float* __restrict__ w,
             const float* __restrict__ g, const float* __restrict__ bb,
             unsigned short* __restrict__ h, long long h_po)
{
    int b = blockIdx.y;
    int p = blockIdx.x * 4 + (threadIdx.x >> 6);
    int c = threadIdx.x & 63;
    const float* xp = x + ((long long)b * NPTS + p) * 3;
    float y = xp[0] * w[c * 3] + xp[1] * w[c * 3 + 1] + xp[2] * w[c * 3 + 2];
    y = y * (INV_STD * g[c]) + bb[c];
    y = fmaxf(y, 0.f);
    long long i = ((long long)b * NPTS + p) * 64 + c;
    unsigned short hi = f2bf(y);
    h[i] = hi;
    h[h_po + i] = f2bf(y - bf2f(hi));
}

// d = x - (sum_ms part)/(1e-9 + sum_ms csp); point-major, 256 channels
__global__ __launch_bounds__(256)
void diff_k(const unsigned short* __restrict__ xin, long long x_bs, int x_ld, long long x_po,
            const float* __restrict__ part, const float* __restrict__ csp,
            unsigned short* __restrict__ d, long long d_po)
{
    long long i = (long long)blockIdx.x * 256 + threadIdx.x;  // over NPTS*256
    int b = blockIdx.y;
    int p = (int)(i >> 8), c = (int)(i & 255);
    long long xi = (long long)b * x_bs + (long long)p * x_ld + c;
    float xv = bf2f(xin[xi]) + bf2f(xin[x_po + xi]);
    float xr = 0.f, den = 1e-9f;
    #pragma unroll
    for (int ks = 0; ks < MSPLIT; ks++) {
        int z = b * MSPLIT + ks;
        xr  += part[(long long)z * ((long long)NPTS * 256) + i];
        den += csp[(long long)z * NPTS + p];
    }
    float v = xv - xr / den;
    long long di = (long long)b * NPTS * 256 + i;
    unsigned short hi = f2bf(v);
    d[di] = hi;
    d[d_po + di] = f2bf(v - bf2f(hi));
}

__global__ __launch_bounds__(256)
void gmaxp_k(const unsigned short* __restrict__ face, long long f_po, float* __restrict__ pm)
{
    int c = blockIdx.x * 256 + threadIdx.x;   // 0..511
    int ch = blockIdx.y;                      // 16 point-chunks
    int b = blockIdx.z;
    float m = -3.4e38f;
    for (int j = 0; j < 256; j++) {
        long long i = ((long long)b * NPTS + ch * 256 + j) * 512 + c;
        m = fmaxf(m, bf2f(face[i]) + bf2f(face[f_po + i]));
    }
    pm[((long long)b * 16 + ch) * 512 + c] = m;
}

__global__ __launch_bounds__(256)
void gmaxr_k(const float* __restrict__ pm, float* __restrict__ gm)
{
    int idx = blockIdx.x * 256 + threadIdx.x;  // over BATCH*512
    int b = idx >> 9, c = idx & 511;
    float m = -3.4e38f;
    for (int ch = 0; ch < 16; ch++)
        m = fmaxf(m, pm[((long long)b * 16 + ch) * 512 + c]);
    gm[idx] = m;
}

__global__ __launch_bounds__(256)
void bias2_k(const float* __restrict__ w, const float* __restrict__ g, float* __restrict__ b2)
{
    int o = blockIdx.x * 256 + threadIdx.x;
    int b = blockIdx.y;
    if (o >= 512) return;
    float s = 0.f;
    for (int c = 0; c < 512; c++) s += w[(long long)o * 1024 + 512 + c] * g[b * 512 + c];
    b2[b * 512 + o] = s;
}

extern "C" void kernel_launch(void* const* d_in, const int* in_sizes, int n_in,
                              void* d_out, int out_size, void* d_ws, size_t ws_size,
                              hipStream_t stream)
{
    const float* x       = (const float*)d_in[0];
    const float* conv1_w = (const float*)d_in[1];
    const float* bn1_g   = (const float*)d_in[2];
    const float* bn1_b   = (const float*)d_in[3];
    const float* conv2_w = (const float*)d_in[4];
    const float* bn2_g   = (const float*)d_in[5];
    const float* bn2_b   = (const float*)d_in[6];
    const float* conv3_w = (const float*)d_in[7];
    const float* bn3_g   = (const float*)d_in[8];
    const float* bn3_b   = (const float*)d_in[9];
    const float* pt1_w   = (const float*)d_in[10];
    const float* pt1_g   = (const float*)d_in[11];
    const float* pt1_b   = (const float*)d_in[12];
    const float* pt2_w   = (const float*)d_in[13];
    const float* pt2_g   = (const float*)d_in[14];
    const float* pt2_b   = (const float*)d_in[15];
    const float* sa_qk[2] = {(const float*)d_in[16], (const float*)d_in[23]};
    const float* sa_vw[2] = {(const float*)d_in[17], (const float*)d_in[24]};
    const float* sa_vb[2] = {(const float*)d_in[18], (const float*)d_in[25]};
    const float* sa_tw[2] = {(const float*)d_in[19], (const float*)d_in[26]};
    const float* sa_tb[2] = {(const float*)d_in[20], (const float*)d_in[27]};
    const float* sa_g[2]  = {(const float*)d_in[21], (const float*)d_in[28]};
    const float* sa_b[2]  = {(const float*)d_in[22], (const float*)d_in[29]};
    const float* cf_w = (const float*)d_in[30];
    const float* cf_g = (const float*)d_in[31];
    const float* cf_b = (const float*)d_in[32];
    const float* s1_w = (const float*)d_in[33];
    const float* s1_g = (const float*)d_in[34];
    const float* s1_b = (const float*)d_in[35];
    const float* s2_w = (const float*)d_in[36];
    const float* s2_g = (const float*)d_in[37];
    const float* s2_b = (const float*)d_in[38];
    const float* s3_w = (const float*)d_in[39];

    char* base = (char*)d_ws;
    size_t off = 0;
    auto alloc = [&](size_t bytes) -> void* {
        void* p = base + off;
        off = (off + bytes + 255) & ~(size_t)255;
        return p;
    };
    const long long N = NPTS;
    const long long PO64   = (long long)BATCH * N * 64;
    const long long PO128  = (long long)BATCH * N * 128;
    const long long PO256  = (long long)BATCH * N * 256;
    const long long PO512  = (long long)BATCH * N * 512;
    const long long PO1024 = (long long)BATCH * N * 1024;

    unsigned short* S1  = (unsigned short*)alloc(2 * PO256 * 2);
    unsigned short* S2  = (unsigned short*)alloc(2 * PO256 * 2);
    unsigned short* Dv  = (unsigned short*)alloc(2 * PO256 * 2);
    unsigned short* cat = (unsigned short*)alloc(2 * PO1024 * 2);
    unsigned short* face = (unsigned short*)alloc(2 * PO512 * 2);
    unsigned short* xq  = (unsigned short*)alloc((size_t)BATCH * N * 128 * 2);
    unsigned short* xv  = (unsigned short*)alloc((size_t)BATCH * 256 * N * 2);
    unsigned short* s1b = (unsigned short*)alloc(2 * PO512 * 2);
    unsigned short* s2b = (unsigned short*)alloc(2 * PO256 * 2);
    float* part = (float*)alloc((size_t)BATCH * MSPLIT * N * 256 * 4);          // 32 MB
    float* csp  = (float*)alloc((size_t)BATCH * MSPLIT * N * 4);
    float* rsp  = (float*)alloc((size_t)RSSPLIT * BATCH * N * 4);               // 256 KB
    float* pm = (float*)alloc((size_t)BATCH * 16 * 512 * 4);
    float* gm = (float*)alloc((size_t)BATCH * 512 * 4);
    float* b2 = (float*)alloc((size_t)BATCH * 512 * 4);
    unsigned short* wb = (unsigned short*)alloc((size_t)3400000 * 2);  // pre-split weights

    // ---- weight pre-split table ----
    WSplit wd;
    const float* wsrc[14] = {conv2_w, conv3_w, pt1_w, pt2_w, sa_qk[0], sa_qk[1],
                             sa_vw[0], sa_vw[1], sa_tw[0], sa_tw[1], cf_w, s1_w, s2_w, s3_w};
    int wn[14] = {128*64, 256*128, 256*256, 256*256, 128*256, 128*256,
                  256*256, 256*256, 256*256, 256*256, 512*1024, 512*1024, 256*512, 50*256};
    long long wo[14]; long long acc_ = 0;
    for (int i = 0; i < 14; i++) { wd.src[i] = wsrc[i]; wd.n[i] = wn[i]; wd.off[i] = acc_; wo[i] = acc_; acc_ += 2LL * wn[i]; }
    presplit_k<<<dim3((512*1024 + 255) / 256, 14), 256, 0, stream>>>(wd, wb);
    auto W = [&](int i) { return wb + wo[i]; };

    auto nt = [&](const unsigned short* A, long long a_bs, int a_lda, long long a_po,
                  const unsigned short* B, long long b_bs, int b_lda, long long b_po,
                  void* C, long long c_bs, int c_ld, long long c_po,
                  int Mrows, int Nb, int K,
                  const float* bias, int bias_mode,
                  const float* bng, const float* bnb,
                  const unsigned short* res, long long res_bs, int res_ld, long long res_po,
                  int act, int out_mode) {
        dim3 g((Nb + 63) / 64, Mrows / 64, BATCH);
        gemm_nt_split<<<g, 256, 0, stream>>>(A, a_bs, a_lda, a_po, B, b_bs, b_lda, b_po,
                                             C, c_bs, c_ld, c_po, Nb, K,
                                             bias, bias_mode, bng, bnb,
                                             res, res_bs, res_ld, res_po, act, out_mode);
    };
    auto ntB = [&](const unsigned short* A, long long a_bs, int a_lda, long long a_po,
                   const unsigned short* B, long long b_bs, int b_lda, long long b_po,
                   void* C, long long c_bs, int c_ld, long long c_po,
                   int Mrows, int Nb, int K,
                   const float* bias, int bias_mode,
                   const float* bng, const float* bnb,
                   const unsigned short* res, long long res_bs, int res_ld, long long res_po,
                   int act, int out_mode) {
        dim3 g((Nb + 63) / 64, Mrows / 64, BATCH);
        gemm_nt_splitB<<<g, 256, 0, stream>>>(A, a_bs, a_lda, a_po, B, b_bs, b_lda, b_po,
                                              C, c_bs, c_ld, c_po, Nb, K,
                                              bias, bias_mode, bng, bnb,
                                              res, res_bs, res_ld, res_po, act, out_mode);
    };

    // ---- stem ----
    conv1_k<<<dim3(NPTS / 4, BATCH), 256, 0, stream>>>(x, conv1_w, bn1_g, bn1_b, S1, PO64);
    nt(S1, N * 64, 64, PO64,    W(0), 0, 64, wn[0],  S2, N * 128, 128, PO128,
       NPTS, 128, 64,  nullptr, 0, bn2_g, bn2_b, nullptr, 0, 0, 0, 1, 0);
    ntB(S2, N * 128, 128, PO128, W(1), 0, 128, wn[1], S1, N * 256, 256, PO256,
        NPTS, 256, 128, nullptr, 0, bn3_g, bn3_b, nullptr, 0, 0, 0, 1, 0);
    ntB(S1, N * 256, 256, PO256, W(2), 0, 256, wn[2], S2, N * 256, 256, PO256,
        NPTS, 256, 256, nullptr, 0, pt1_g, pt1_b, nullptr, 0, 0, 0, 1, 0);
    ntB(S2, N * 256, 256, PO256, W(3), 0, 256, wn[3], S1, N * 256, 256, PO256,
        NPTS, 256, 256, nullptr, 0, pt2_g, pt2_b, nullptr, 0, 0, 0, 1, 0);

    // ---- 4 SA layers ----
    for (int i = 0; i < 4; i++) {
        int p = (i == 0) ? 0 : 1;
        const unsigned short* xin = (i == 0) ? S1 : cat + (size_t)(i - 1) * 256;
        long long xin_bs = (i == 0) ? N * 256 : N * 1024;
        int xin_ld = (i == 0) ? 256 : 1024;
        long long xin_po = (i == 0) ? PO256 : PO1024;

        // xq[n][128] plain bf16 (K=256)
        ntB(xin, xin_bs, xin_ld, xin_po, W(4 + p), 0, 256, wn[4 + p],
            xq, N * 128, 128, 0, NPTS, 128, 256,
            nullptr, 0, nullptr, nullptr, nullptr, 0, 0, 0, 0, 1);
        // xv[c][n] plain bf16 (A = weights, K=256)
        ntB(W(6 + p), 0, 256, wn[6 + p], xin, xin_bs, xin_ld, xin_po,
            xv, 256 * N, NPTS, 0, 256, NPTS, 256,
            sa_vb[p], 3, nullptr, nullptr, nullptr, 0, 0, 0, 0, 1);
        // E1: rs partials (plain stores, no zero pass, no atomics)
        rs_k<<<dim3(RSSPLIT, NPTS / 64, BATCH), 256, 0, stream>>>(xq, rsp);
        // E2: fused QK->exp/rs->PV partials + cs partials (Vv latency hidden)
        attn_pv<<<dim3(1, NPTS / 64, BATCH * MSPLIT), 256, 0, stream>>>(
            xq, xv, rsp, part, csp);
        // d = x - (sum partials)/(1e-9 + sum cs partials)
        diff_k<<<dim3(NPTS * 256 / 256, BATCH), 256, 0, stream>>>(
            xin, xin_bs, xin_ld, xin_po, part, csp, Dv, PO256);
        // x_out = x + relu(bn(tw@d + tb)) -> cat slice i (K=256)
        ntB(Dv, N * 256, 256, PO256, W(8 + p), 0, 256, wn[8 + p],
            cat + (size_t)i * 256, N * 1024, 1024, PO1024,
            NPTS, 256, 256, sa_tb[p], 1, sa_g[p], sa_b[p],
            xin, xin_bs, xin_ld, xin_po, 1, 0);
    }

    // ---- head ----
    nt(cat, N * 1024, 1024, PO1024, W(10), 0, 1024, wn[10],
       face, N * 512, 512, PO512, NPTS, 512, 1024,
       nullptr, 0, cf_g, cf_b, nullptr, 0, 0, 0, 2, 0);
    gmaxp_k<<<dim3(2, 16, BATCH), 256, 0, stream>>>(face, PO512, pm);
    gmaxr_k<<<dim3(BATCH * 512 / 256), 256, 0, stream>>>(pm, gm);
    bias2_k<<<dim3(2, BATCH), 256, 0, stream>>>(s1_w, gm, b2);
    nt(face, N * 512, 512, PO512, W(11), 0, 1024, wn[11],
       s1b, N * 512, 512, PO512, NPTS, 512, 512,
       b2, 2, s1_g, s1_b, nullptr, 0, 0, 0, 2, 0);
    ntB(s1b, N * 512, 512, PO512, W(12), 0, 512, wn[12],
        s2b, N * 256, 256, PO256, NPTS, 256, 512,
        nullptr, 0, s2_g, s2_b, nullptr, 0, 0, 0, 2, 0);
    ntB(s2b, N * 256, 256, PO256, W(13), 0, 256, wn[13],
        d_out, N * 50, 50, 0, NPTS, 50, 256,
        nullptr, 0, nullptr, nullptr, nullptr, 0, 0, 0, 0, 2);
}

// Round 17
// 779.570 us; speedup vs baseline: 1.0445x; 1.0445x over previous
//
#include <hip/hip_runtime.h>
#include <hip/hip_bf16.h>

// PCT segmentation forward. R17 = exact resubmission of R13 (best: 780us).
// Consolidation: R15/R16's attn_pv reorder + rsp partials both regressed
// (uncovered Kq-only drain; 8x rs loads in hot loop). R13 configuration:
// - trunk: K1 (BK=64) for conv2/cf/s1 (1024-block calls), ntB (BK=128,
//   64KB LDS, half the barriers, bit-identical) for all K%128==0 calls.
// - attention: rs_k (atomic row-sums) -> attn_pv (joint Kq+Vv staging,
//   inline 1/rs, 64p x 256c register PV, plain per-chunk partials + csp).
// - split-bf16 (hi/lo) everywhere outside attention: fp32-level accuracy.

#define NPTS 4096
#define BATCH 2
#define MSPLIT 4
#define RSSPLIT 8
static constexpr float INV_STD = 0.9999950000374997f;  // 1/sqrt(1+1e-5)

__device__ __forceinline__ float bf2f(unsigned short u) {
    return __uint_as_float(((unsigned int)u) << 16);
}
__device__ __forceinline__ unsigned short f2bf(float f) {
    unsigned int x = __float_as_uint(f);
    unsigned int r = (x + 0x7FFFu + ((x >> 16) & 1u)) >> 16;
    return (unsigned short)r;
}

// async global->LDS 16B DMA: LDS base wave-uniform; HW writes lptr+lane*16.
__device__ __forceinline__ void async16(const unsigned short* g, unsigned short* l)
{
    __builtin_amdgcn_global_load_lds(
        (const __attribute__((address_space(1))) unsigned int*)(const void*)g,
        (__attribute__((address_space(3))) unsigned int*)(void*)l,
        16, 0, 0);
}

typedef __attribute__((ext_vector_type(8))) short short8;
typedef __attribute__((ext_vector_type(4))) float f32x4;

// ---------------- weight pre-split ----------------
struct WSplit {
    const float* src[14];
    int n[14];
    long long off[14];   // ushort offset of hi plane; lo at off+n
};

__global__ __launch_bounds__(256)
void presplit_k(WSplit d, unsigned short* __restrict__ wbuf)
{
    int wi = blockIdx.y;
    int i = blockIdx.x * 256 + threadIdx.x;
    int n = d.n[wi];
    if (i >= n) return;
    float v = d.src[wi][i];
    unsigned short h = f2bf(v);
    unsigned short* dst = wbuf + d.off[wi];
    dst[i] = h;
    dst[n + i] = f2bf(v - bf2f(h));
}

// shared epilogue
__device__ __forceinline__ void nt_epilogue(
    float y, int rg, int cg, int b, int Nb,
    const float* bias, int bias_mode,
    const float* bng, const float* bnb,
    const unsigned short* res, long long res_bs, int res_ld, long long res_po,
    int act, int out_mode,
    void* Cp, long long c_bs, int c_ld, long long c_po)
{
    if (bias) {
        if (bias_mode == 3)      y += bias[rg];
        else if (bias_mode == 2) y += bias[b * Nb + cg];
        else                     y += bias[cg];
    }
    if (bng) y = y * (INV_STD * bng[cg]) + bnb[cg];
    if (act == 1) y = fmaxf(y, 0.f);
    else if (act == 2) y = (y > 0.f) ? y : 0.2f * y;
    if (res) {
        long long ri_ = (long long)b * res_bs + (long long)rg * res_ld + cg;
        y += bf2f(res[ri_]) + bf2f(res[res_po + ri_]);
    }
    long long ci = (long long)b * c_bs + (long long)rg * c_ld + cg;
    if (out_mode == 0) {
        unsigned short* C = (unsigned short*)Cp;
        unsigned short h = f2bf(y);
        C[ci] = h;
        C[c_po + ci] = f2bf(y - bf2f(h));
    } else if (out_mode == 1) {
        ((unsigned short*)Cp)[ci] = f2bf(y);
    } else {
        if (cg < Nb) ((float*)Cp)[ci] = y;
    }
}

// ---------------- K1: split-bf16 NT GEMM, 64x64 tile, BK=64 ----------------
__global__ __launch_bounds__(256)
void gemm_nt_split(const unsigned short* __restrict__ A, long long a_bs, int a_lda, long long a_po,
                   const unsigned short* __restrict__ B, long long b_bs, int b_lda, long long b_po,
                   void* __restrict__ Cp, long long c_bs, int c_ld, long long c_po,
                   int Nb, int K,
                   const float* __restrict__ bias, int bias_mode,
                   const float* __restrict__ bng, const float* __restrict__ bnb,
                   const unsigned short* __restrict__ res, long long res_bs, int res_ld, long long res_po,
                   int act, int out_mode)
{
    __shared__ unsigned short As[2][64 * 64];
    __shared__ unsigned short Bs[2][64 * 64];
    const int b = blockIdx.z;
    const int m0 = blockIdx.y * 64, n0 = blockIdx.x * 64;
    const int t = threadIdx.x;
    const int lane = t & 63, w = t >> 6;
    const int wr = (w >> 1) * 32, wc = (w & 1) * 32;
    const int ml = lane & 15, q = lane >> 4;

    f32x4 acc[2][2] = {};

    for (int k0 = 0; k0 < K; k0 += 64) {
        __syncthreads();
        #pragma unroll
        for (int e = 0; e < 2; e++) {
            int idx = t + e * 256;
            int row = idx >> 3, blk = idx & 7;
            int gblk = blk ^ (row & 7);
            int lofs = (e * 256 + (t & 192)) * 8;
            const unsigned short* sA = A + (long long)b * a_bs
                                     + (long long)(m0 + row) * a_lda + k0 + gblk * 8;
            const unsigned short* sB = B + (long long)b * b_bs
                                     + (long long)(n0 + row) * b_lda + k0 + gblk * 8;
            async16(sA,        &As[0][0] + lofs);
            async16(sA + a_po, &As[1][0] + lofs);
            async16(sB,        &Bs[0][0] + lofs);
            async16(sB + b_po, &Bs[1][0] + lofs);
        }
        __syncthreads();
        #pragma unroll
        for (int kk = 0; kk < 2; kk++) {
            short8 ah[2], al[2], bh[2], bl[2];
            #pragma unroll
            for (int it = 0; it < 2; it++) {
                int row = wr + it * 16 + ml;
                int slot = (kk * 4 + q) ^ (row & 7);
                ah[it] = *(const short8*)(&As[0][row * 64 + slot * 8]);
                al[it] = *(const short8*)(&As[1][row * 64 + slot * 8]);
            }
            #pragma unroll
            for (int jt = 0; jt < 2; jt++) {
                int row = wc + jt * 16 + ml;
                int slot = (kk * 4 + q) ^ (row & 7);
                bh[jt] = *(const short8*)(&Bs[0][row * 64 + slot * 8]);
                bl[jt] = *(const short8*)(&Bs[1][row * 64 + slot * 8]);
            }
            #pragma unroll
            for (int it = 0; it < 2; it++)
                #pragma unroll
                for (int jt = 0; jt < 2; jt++) {
                    acc[it][jt] = __builtin_amdgcn_mfma_f32_16x16x32_bf16(ah[it], bh[jt], acc[it][jt], 0, 0, 0);
                    acc[it][jt] = __builtin_amdgcn_mfma_f32_16x16x32_bf16(ah[it], bl[jt], acc[it][jt], 0, 0, 0);
                    acc[it][jt] = __builtin_amdgcn_mfma_f32_16x16x32_bf16(al[it], bh[jt], acc[it][jt], 0, 0, 0);
                }
        }
    }

    #pragma unroll
    for (int it = 0; it < 2; it++)
        #pragma unroll
        for (int jt = 0; jt < 2; jt++)
            #pragma unroll
            for (int r = 0; r < 4; r++)
                nt_epilogue(acc[it][jt][r], m0 + wr + it * 16 + q * 4 + r,
                            n0 + wc + jt * 16 + ml, b, Nb,
                            bias, bias_mode, bng, bnb, res, res_bs, res_ld, res_po,
                            act, out_mode, Cp, c_bs, c_ld, c_po);
}

// ---------------- K1B: split-bf16 NT GEMM, 64x64 tile, BK=128 ----------------
__global__ __launch_bounds__(256)
void gemm_nt_splitB(const unsigned short* __restrict__ A, long long a_bs, int a_lda, long long a_po,
                    const unsigned short* __restrict__ B, long long b_bs, int b_lda, long long b_po,
                    void* __restrict__ Cp, long long c_bs, int c_ld, long long c_po,
                    int Nb, int K,
                    const float* __restrict__ bias, int bias_mode,
                    const float* __restrict__ bng, const float* __restrict__ bnb,
                    const unsigned short* __restrict__ res, long long res_bs, int res_ld, long long res_po,
                    int act, int out_mode)
{
    __shared__ unsigned short As[2][2][64 * 64];   // [plane][sub] 32 KB
    __shared__ unsigned short Bs[2][2][64 * 64];   // 32 KB
    const int b = blockIdx.z;
    const int m0 = blockIdx.y * 64, n0 = blockIdx.x * 64;
    const int t = threadIdx.x;
    const int lane = t & 63, w = t >> 6;
    const int wr = (w >> 1) * 32, wc = (w & 1) * 32;
    const int ml = lane & 15, q = lane >> 4;

    f32x4 acc[2][2] = {};

    for (int k0 = 0; k0 < K; k0 += 128) {
        __syncthreads();
        #pragma unroll
        for (int sub = 0; sub < 2; sub++) {
            int kb = k0 + sub * 64;
            #pragma unroll
            for (int e = 0; e < 2; e++) {
                int idx = t + e * 256;
                int row = idx >> 3, blk = idx & 7;
                int gblk = blk ^ (row & 7);
                int lofs = (e * 256 + (t & 192)) * 8;
                const unsigned short* sA = A + (long long)b * a_bs
                                         + (long long)(m0 + row) * a_lda + kb + gblk * 8;
                const unsigned short* sB = B + (long long)b * b_bs
                                         + (long long)(n0 + row) * b_lda + kb + gblk * 8;
                async16(sA,        &As[0][sub][0] + lofs);
                async16(sA + a_po, &As[1][sub][0] + lofs);
                async16(sB,        &Bs[0][sub][0] + lofs);
                async16(sB + b_po, &Bs[1][sub][0] + lofs);
            }
        }
        __syncthreads();
        #pragma unroll
        for (int sub = 0; sub < 2; sub++)
            #pragma unroll
            for (int kk = 0; kk < 2; kk++) {
                short8 ah[2], al[2], bh[2], bl[2];
                #pragma unroll
                for (int it = 0; it < 2; it++) {
                    int row = wr + it * 16 + ml;
                    int slot = (kk * 4 + q) ^ (row & 7);
                    ah[it] = *(const short8*)(&As[0][sub][row * 64 + slot * 8]);
                    al[it] = *(const short8*)(&As[1][sub][row * 64 + slot * 8]);
                }
                #pragma unroll
                for (int jt = 0; jt < 2; jt++) {
                    int row = wc + jt * 16 + ml;
                    int slot = (kk * 4 + q) ^ (row & 7);
                    bh[jt] = *(const short8*)(&Bs[0][sub][row * 64 + slot * 8]);
                    bl[jt] = *(const short8*)(&Bs[1][sub][row * 64 + slot * 8]);
                }
                #pragma unroll
                for (int it = 0; it < 2; it++)
                    #pragma unroll
                    for (int jt = 0; jt < 2; jt++) {
                        acc[it][jt] = __builtin_amdgcn_mfma_f32_16x16x32_bf16(ah[it], bh[jt], acc[it][jt], 0, 0, 0);
                        acc[it][jt] = __builtin_amdgcn_mfma_f32_16x16x32_bf16(ah[it], bl[jt], acc[it][jt], 0, 0, 0);
                        acc[it][jt] = __builtin_amdgcn_mfma_f32_16x16x32_bf16(al[it], bh[jt], acc[it][jt], 0, 0, 0);
                    }
            }
    }

    #pragma unroll
    for (int it = 0; it < 2; it++)
        #pragma unroll
        for (int jt = 0; jt < 2; jt++)
            #pragma unroll
            for (int r = 0; r < 4; r++)
                nt_epilogue(acc[it][jt][r], m0 + wr + it * 16 + q * 4 + r,
                            n0 + wc + jt * 16 + ml, b, Nb,
                            bias, bias_mode, bng, bnb, res, res_bs, res_ld, res_po,
                            act, out_mode, Cp, c_bs, c_ld, c_po);
}

// ---------------- E1: rs[p] = sum_m exp(e[p][m]), atomic row-sums ----------------
__global__ __launch_bounds__(256)
void rs_k(const unsigned short* __restrict__ xq, float* __restrict__ rs)
{
    __shared__ unsigned short Kq[2][64 * 64];
    const int b = blockIdx.z;
    const int p0 = blockIdx.y * 64;
    const int m_beg = blockIdx.x * (NPTS / RSSPLIT);
    const unsigned short* xqB = xq + (long long)b * NPTS * 128;
    const int t = threadIdx.x;
    const int lane = t & 63, w = t >> 6;
    const int pw = w * 16;
    const int ml = lane & 15, q = lane >> 4;

    short8 af[4];
    #pragma unroll
    for (int ks = 0; ks < 4; ks++)
        af[ks] = *(const short8*)(xqB + (long long)(p0 + pw + ml) * 128 + ks * 32 + q * 8);

    float rsum[4] = {0.f, 0.f, 0.f, 0.f};

    for (int m0 = m_beg; m0 < m_beg + NPTS / RSSPLIT; m0 += 64) {
        __syncthreads();
        #pragma unroll
        for (int e = 0; e < 4; e++) {
            int idx = t + e * 256;
            int sub = idx >> 9, row = (idx >> 3) & 63, blk = idx & 7;
            int gblk = blk ^ (row & 7);
            int lofs = (e * 256 + (t & 192)) * 8;
            async16(xqB + (long long)(m0 + row) * 128 + sub * 64 + gblk * 8,
                    &Kq[0][0] + lofs);
        }
        __syncthreads();
        f32x4 acc[4] = {};
        #pragma unroll
        for (int ks = 0; ks < 4; ks++) {
            int kh = ks >> 1, kk = ks & 1;
            #pragma unroll
            for (int jt = 0; jt < 4; jt++) {
                int row = jt * 16 + ml;
                int slot = (kk * 4 + q) ^ (row & 7);
                short8 bf = *(const short8*)(&Kq[kh][row * 64 + slot * 8]);
                acc[jt] = __builtin_amdgcn_mfma_f32_16x16x32_bf16(af[ks], bf, acc[jt], 0, 0, 0);
            }
        }
        #pragma unroll
        for (int jt = 0; jt < 4; jt++)
            #pragma unroll
            for (int r = 0; r < 4; r++)
                rsum[r] += __expf(acc[jt][r]);
    }
    #pragma unroll
    for (int r = 0; r < 4; r++) {
        float s = rsum[r];
        s += __shfl_xor(s, 1); s += __shfl_xor(s, 2);
        s += __shfl_xor(s, 4); s += __shfl_xor(s, 8);
        if (ml == 0) atomicAdd(&rs[b * NPTS + p0 + pw + q * 4 + r], s);
    }
}

// ---------------- E2: QK -> exp/rs[m] -> PV partials + cs partials ----------------
__global__ __launch_bounds__(256)
void attn_pv(const unsigned short* __restrict__ xq,   // [B][N][128]
             const unsigned short* __restrict__ xv,   // [B][256][N]
             const float* __restrict__ rs,
             float* __restrict__ part,                // [B*MSPLIT][N][256]
             float* __restrict__ csp)                 // [B*MSPLIT][N]
{
    __shared__ unsigned short Kq[2][64 * 64];   // 16 KB
    __shared__ unsigned short Vv[256 * 64];     // 32 KB
    __shared__ unsigned short Pl[64][72];       // 9.2 KB
    const int z = blockIdx.z, b = z / MSPLIT, ms = z % MSPLIT;
    const int p0 = blockIdx.y * 64;
    const unsigned short* xqB = xq + (long long)b * NPTS * 128;
    const unsigned short* xvB = xv + (long long)b * 256 * NPTS;
    const float* rsB = rs + b * NPTS;
    const int t = threadIdx.x;
    const int lane = t & 63, w = t >> 6;
    const int pw = w * 16;                      // QK p-strip
    const int cw = w * 64;                      // PV c-strip
    const int ml = lane & 15, q = lane >> 4;

    short8 af[4];
    #pragma unroll
    for (int ks = 0; ks < 4; ks++)
        af[ks] = *(const short8*)(xqB + (long long)(p0 + pw + ml) * 128 + ks * 32 + q * 8);

    f32x4 pv[4][4] = {};                        // [p-tile][c-tile]
    float csr[4] = {0.f, 0.f, 0.f, 0.f};

    const int m_beg = ms * (NPTS / MSPLIT);
    for (int m0 = m_beg; m0 < m_beg + NPTS / MSPLIT; m0 += 64) {
        __syncthreads();
        #pragma unroll
        for (int e = 0; e < 4; e++) {
            int idx = t + e * 256;
            int sub = idx >> 9, row = (idx >> 3) & 63, blk = idx & 7;
            int gblk = blk ^ (row & 7);
            int lofs = (e * 256 + (t & 192)) * 8;
            async16(xqB + (long long)(m0 + row) * 128 + sub * 64 + gblk * 8,
                    &Kq[0][0] + lofs);
        }
        #pragma unroll
        for (int e = 0; e < 8; e++) {
            int idx = t + e * 256;
            int row = idx >> 3, blk = idx & 7;
            int gblk = blk ^ (row & 7);
            int lofs = (e * 256 + (t & 192)) * 8;
            async16(xvB + (long long)row * NPTS + m0 + gblk * 8, Vv + lofs);
        }
        __syncthreads();
        // QK: e[p64][m64]; this wave: p-strip pw (identical chain to rs_k)
        f32x4 acc[4] = {};
        #pragma unroll
        for (int ks = 0; ks < 4; ks++) {
            int kh = ks >> 1, kk = ks & 1;
            #pragma unroll
            for (int jt = 0; jt < 4; jt++) {
                int row = jt * 16 + ml;
                int slot = (kk * 4 + q) ^ (row & 7);
                short8 bf = *(const short8*)(&Kq[kh][row * 64 + slot * 8]);
                acc[jt] = __builtin_amdgcn_mfma_f32_16x16x32_bf16(af[ks], bf, acc[jt], 0, 0, 0);
            }
        }
        // P' = exp(e)/rs[m]
        #pragma unroll
        for (int jt = 0; jt < 4; jt++) {
            float rvm = 1.f / rsB[m0 + jt * 16 + ml];
            #pragma unroll
            for (int r = 0; r < 4; r++) {
                float pvv = __expf(acc[jt][r]) * rvm;
                csr[r] += pvv;
                Pl[pw + q * 4 + r][jt * 16 + ml] = f2bf(pvv);
            }
        }
        __syncthreads();
        // PV: this wave c-strip cw; A = P'[64p][64m] (shared), B = Vv rows
        #pragma unroll
        for (int kk = 0; kk < 2; kk++) {
            short8 ap[4];
            #pragma unroll
            for (int pst = 0; pst < 4; pst++)
                ap[pst] = *(const short8*)(&Pl[pst * 16 + ml][kk * 32 + q * 8]);
            #pragma unroll
            for (int jt = 0; jt < 4; jt++) {
                int row = cw + jt * 16 + ml;
                int slot = (kk * 4 + q) ^ (row & 7);
                short8 bv = *(const short8*)(&Vv[row * 64 + slot * 8]);
                #pragma unroll
                for (int pst = 0; pst < 4; pst++)
                    pv[pst][jt] = __builtin_amdgcn_mfma_f32_16x16x32_bf16(
                        ap[pst], bv, pv[pst][jt], 0, 0, 0);
            }
        }
    }
    // cs partial: reduce over 16 m-lanes, one PLAIN store per (z, p-row)
    #pragma unroll
    for (int r = 0; r < 4; r++) {
        float s = csr[r];
        s += __shfl_xor(s, 1); s += __shfl_xor(s, 2);
        s += __shfl_xor(s, 4); s += __shfl_xor(s, 8);
        if (ml == 0) csp[(long long)z * NPTS + p0 + pw + q * 4 + r] = s;
    }
    // store PV partials (plain f32)
    float* C = part + (long long)z * ((long long)NPTS * 256);
    #pragma unroll
    for (int pst = 0; pst < 4; pst++)
        #pragma unroll
        for (int jt = 0; jt < 4; jt++)
            #pragma unroll
            for (int r = 0; r < 4; r++) {
                int rg = p0 + pst * 16 + q * 4 + r;
                int cg = cw + jt * 16 + ml;
                C[(long long)rg * 256 + cg] = pv[pst][jt][r];
            }
}

// ---------------- small kernels ----------------
__global__ __launch_bounds__(256)
void conv1_k(const float* __restrict__ x, const float* __restrict__ w,
             const float* __restrict__ g, const float* __restrict__ bb,
             unsigned short* __restrict__ h, long long h_po)
{
    int b = blockIdx.y;
    int p = blockIdx.x * 4 + (threadIdx.x >> 6);
    int c = threadIdx.x & 63;
    const float* xp = x + ((long long)b * NPTS + p) * 3;
    float y = xp[0] * w[c * 3] + xp[1] * w[c * 3 + 1] + xp[2] * w[c * 3 + 2];
    y = y * (INV_STD * g[c]) + bb[c];
    y = fmaxf(y, 0.f);
    long long i = ((long long)b * NPTS + p) * 64 + c;
    unsigned short hi = f2bf(y);
    h[i] = hi;
    h[h_po + i] = f2bf(y - bf2f(hi));
}

__global__ __launch_bounds__(256)
void zero_k(float* __restrict__ p, int n)
{
    int i = blockIdx.x * 256 + threadIdx.x;
    if (i < n) p[i] = 0.f;
}

// d = x - (sum_ms part)/(1e-9 + sum_ms csp); point-major, 256 channels
__global__ __launch_bounds__(256)
void diff_k(const unsigned short* __restrict__ xin, long long x_bs, int x_ld, long long x_po,
            const float* __restrict__ part, const float* __restrict__ csp,
            unsigned short* __restrict__ d, long long d_po)
{
    long long i = (long long)blockIdx.x * 256 + threadIdx.x;  // over NPTS*256
    int b = blockIdx.y;
    int p = (int)(i >> 8), c = (int)(i & 255);
    long long xi = (long long)b * x_bs + (long long)p * x_ld + c;
    float xv = bf2f(xin[xi]) + bf2f(xin[x_po + xi]);
    float xr = 0.f, den = 1e-9f;
    #pragma unroll
    for (int ks = 0; ks < MSPLIT; ks++) {
        int z = b * MSPLIT + ks;
        xr  += part[(long long)z * ((long long)NPTS * 256) + i];
        den += csp[(long long)z * NPTS + p];
    }
    float v = xv - xr / den;
    long long di = (long long)b * NPTS * 256 + i;
    unsigned short hi = f2bf(v);
    d[di] = hi;
    d[d_po + di] = f2bf(v - bf2f(hi));
}

__global__ __launch_bounds__(256)
void gmaxp_k(const unsigned short* __restrict__ face, long long f_po, float* __restrict__ pm)
{
    int c = blockIdx.x * 256 + threadIdx.x;   // 0..511
    int ch = blockIdx.y;                      // 16 point-chunks
    int b = blockIdx.z;
    float m = -3.4e38f;
    for (int j = 0; j < 256; j++) {
        long long i = ((long long)b * NPTS + ch * 256 + j) * 512 + c;
        m = fmaxf(m, bf2f(face[i]) + bf2f(face[f_po + i]));
    }
    pm[((long long)b * 16 + ch) * 512 + c] = m;
}

__global__ __launch_bounds__(256)
void gmaxr_k(const float* __restrict__ pm, float* __restrict__ gm)
{
    int idx = blockIdx.x * 256 + threadIdx.x;  // over BATCH*512
    int b = idx >> 9, c = idx & 511;
    float m = -3.4e38f;
    for (int ch = 0; ch < 16; ch++)
        m = fmaxf(m, pm[((long long)b * 16 + ch) * 512 + c]);
    gm[idx] = m;
}

__global__ __launch_bounds__(256)
void bias2_k(const float* __restrict__ w, const float* __restrict__ g, float* __restrict__ b2)
{
    int o = blockIdx.x * 256 + threadIdx.x;
    int b = blockIdx.y;
    if (o >= 512) return;
    float s = 0.f;
    for (int c = 0; c < 512; c++) s += w[(long long)o * 1024 + 512 + c] * g[b * 512 + c];
    b2[b * 512 + o] = s;
}

extern "C" void kernel_launch(void* const* d_in, const int* in_sizes, int n_in,
                              void* d_out, int out_size, void* d_ws, size_t ws_size,
                              hipStream_t stream)
{
    const float* x       = (const float*)d_in[0];
    const float* conv1_w = (const float*)d_in[1];
    const float* bn1_g   = (const float*)d_in[2];
    const float* bn1_b   = (const float*)d_in[3];
    const float* conv2_w = (const float*)d_in[4];
    const float* bn2_g   = (const float*)d_in[5];
    const float* bn2_b   = (const float*)d_in[6];
    const float* conv3_w = (const float*)d_in[7];
    const float* bn3_g   = (const float*)d_in[8];
    const float* bn3_b   = (const float*)d_in[9];
    const float* pt1_w   = (const float*)d_in[10];
    const float* pt1_g   = (const float*)d_in[11];
    const float* pt1_b   = (const float*)d_in[12];
    const float* pt2_w   = (const float*)d_in[13];
    const float* pt2_g   = (const float*)d_in[14];
    const float* pt2_b   = (const float*)d_in[15];
    const float* sa_qk[2] = {(const float*)d_in[16], (const float*)d_in[23]};
    const float* sa_vw[2] = {(const float*)d_in[17], (const float*)d_in[24]};
    const float* sa_vb[2] = {(const float*)d_in[18], (const float*)d_in[25]};
    const float* sa_tw[2] = {(const float*)d_in[19], (const float*)d_in[26]};
    const float* sa_tb[2] = {(const float*)d_in[20], (const float*)d_in[27]};
    const float* sa_g[2]  = {(const float*)d_in[21], (const float*)d_in[28]};
    const float* sa_b[2]  = {(const float*)d_in[22], (const float*)d_in[29]};
    const float* cf_w = (const float*)d_in[30];
    const float* cf_g = (const float*)d_in[31];
    const float* cf_b = (const float*)d_in[32];
    const float* s1_w = (const float*)d_in[33];
    const float* s1_g = (const float*)d_in[34];
    const float* s1_b = (const float*)d_in[35];
    const float* s2_w = (const float*)d_in[36];
    const float* s2_g = (const float*)d_in[37];
    const float* s2_b = (const float*)d_in[38];
    const float* s3_w = (const float*)d_in[39];

    char* base = (char*)d_ws;
    size_t off = 0;
    auto alloc = [&](size_t bytes) -> void* {
        void* p = base + off;
        off = (off + bytes + 255) & ~(size_t)255;
        return p;
    };
    const long long N = NPTS;
    const long long PO64   = (long long)BATCH * N * 64;
    const long long PO128  = (long long)BATCH * N * 128;
    const long long PO256  = (long long)BATCH * N * 256;
    const long long PO512  = (long long)BATCH * N * 512;
    const long long PO1024 = (long long)BATCH * N * 1024;

    unsigned short* S1  = (unsigned short*)alloc(2 * PO256 * 2);
    unsigned short* S2  = (unsigned short*)alloc(2 * PO256 * 2);
    unsigned short* Dv  = (unsigned short*)alloc(2 * PO256 * 2);
    unsigned short* cat = (unsigned short*)alloc(2 * PO1024 * 2);
    unsigned short* face = (unsigned short*)alloc(2 * PO512 * 2);
    unsigned short* xq  = (unsigned short*)alloc((size_t)BATCH * N * 128 * 2);
    unsigned short* xv  = (unsigned short*)alloc((size_t)BATCH * 256 * N * 2);
    unsigned short* s1b = (unsigned short*)alloc(2 * PO512 * 2);
    unsigned short* s2b = (unsigned short*)alloc(2 * PO256 * 2);
    float* part = (float*)alloc((size_t)BATCH * MSPLIT * N * 256 * 4);          // 32 MB
    float* csp  = (float*)alloc((size_t)BATCH * MSPLIT * N * 4);
    float* rs = (float*)alloc((size_t)BATCH * N * 4);
    float* pm = (float*)alloc((size_t)BATCH * 16 * 512 * 4);
    float* gm = (float*)alloc((size_t)BATCH * 512 * 4);
    float* b2 = (float*)alloc((size_t)BATCH * 512 * 4);
    unsigned short* wb = (unsigned short*)alloc((size_t)3400000 * 2);  // pre-split weights

    // ---- weight pre-split table ----
    WSplit wd;
    const float* wsrc[14] = {conv2_w, conv3_w, pt1_w, pt2_w, sa_qk[0], sa_qk[1],
                             sa_vw[0], sa_vw[1], sa_tw[0], sa_tw[1], cf_w, s1_w, s2_w, s3_w};
    int wn[14] = {128*64, 256*128, 256*256, 256*256, 128*256, 128*256,
                  256*256, 256*256, 256*256, 256*256, 512*1024, 512*1024, 256*512, 50*256};
    long long wo[14]; long long acc_ = 0;
    for (int i = 0; i < 14; i++) { wd.src[i] = wsrc[i]; wd.n[i] = wn[i]; wd.off[i] = acc_; wo[i] = acc_; acc_ += 2LL * wn[i]; }
    presplit_k<<<dim3((512*1024 + 255) / 256, 14), 256, 0, stream>>>(wd, wb);
    auto W = [&](int i) { return wb + wo[i]; };

    auto nt = [&](const unsigned short* A, long long a_bs, int a_lda, long long a_po,
                  const unsigned short* B, long long b_bs, int b_lda, long long b_po,
                  void* C, long long c_bs, int c_ld, long long c_po,
                  int Mrows, int Nb, int K,
                  const float* bias, int bias_mode,
                  const float* bng, const float* bnb,
                  const unsigned short* res, long long res_bs, int res_ld, long long res_po,
                  int act, int out_mode) {
        dim3 g((Nb + 63) / 64, Mrows / 64, BATCH);
        gemm_nt_split<<<g, 256, 0, stream>>>(A, a_bs, a_lda, a_po, B, b_bs, b_lda, b_po,
                                             C, c_bs, c_ld, c_po, Nb, K,
                                             bias, bias_mode, bng, bnb,
                                             res, res_bs, res_ld, res_po, act, out_mode);
    };
    auto ntB = [&](const unsigned short* A, long long a_bs, int a_lda, long long a_po,
                   const unsigned short* B, long long b_bs, int b_lda, long long b_po,
                   void* C, long long c_bs, int c_ld, long long c_po,
                   int Mrows, int Nb, int K,
                   const float* bias, int bias_mode,
                   const float* bng, const float* bnb,
                   const unsigned short* res, long long res_bs, int res_ld, long long res_po,
                   int act, int out_mode) {
        dim3 g((Nb + 63) / 64, Mrows / 64, BATCH);
        gemm_nt_splitB<<<g, 256, 0, stream>>>(A, a_bs, a_lda, a_po, B, b_bs, b_lda, b_po,
                                              C, c_bs, c_ld, c_po, Nb, K,
                                              bias, bias_mode, bng, bnb,
                                              res, res_bs, res_ld, res_po, act, out_mode);
    };

    // ---- stem ----
    conv1_k<<<dim3(NPTS / 4, BATCH), 256, 0, stream>>>(x, conv1_w, bn1_g, bn1_b, S1, PO64);
    nt(S1, N * 64, 64, PO64,    W(0), 0, 64, wn[0],  S2, N * 128, 128, PO128,
       NPTS, 128, 64,  nullptr, 0, bn2_g, bn2_b, nullptr, 0, 0, 0, 1, 0);
    ntB(S2, N * 128, 128, PO128, W(1), 0, 128, wn[1], S1, N * 256, 256, PO256,
        NPTS, 256, 128, nullptr, 0, bn3_g, bn3_b, nullptr, 0, 0, 0, 1, 0);
    ntB(S1, N * 256, 256, PO256, W(2), 0, 256, wn[2], S2, N * 256, 256, PO256,
        NPTS, 256, 256, nullptr, 0, pt1_g, pt1_b, nullptr, 0, 0, 0, 1, 0);
    ntB(S2, N * 256, 256, PO256, W(3), 0, 256, wn[3], S1, N * 256, 256, PO256,
        NPTS, 256, 256, nullptr, 0, pt2_g, pt2_b, nullptr, 0, 0, 0, 1, 0);

    // ---- 4 SA layers ----
    for (int i = 0; i < 4; i++) {
        int p = (i == 0) ? 0 : 1;
        const unsigned short* xin = (i == 0) ? S1 : cat + (size_t)(i - 1) * 256;
        long long xin_bs = (i == 0) ? N * 256 : N * 1024;
        int xin_ld = (i == 0) ? 256 : 1024;
        long long xin_po = (i == 0) ? PO256 : PO1024;

        // xq[n][128] plain bf16 (K=256)
        ntB(xin, xin_bs, xin_ld, xin_po, W(4 + p), 0, 256, wn[4 + p],
            xq, N * 128, 128, 0, NPTS, 128, 256,
            nullptr, 0, nullptr, nullptr, nullptr, 0, 0, 0, 0, 1);
        // xv[c][n] plain bf16 (A = weights, K=256)
        ntB(W(6 + p), 0, 256, wn[6 + p], xin, xin_bs, xin_ld, xin_po,
            xv, 256 * N, NPTS, 0, 256, NPTS, 256,
            sa_vb[p], 3, nullptr, nullptr, nullptr, 0, 0, 0, 0, 1);
        // zero rs (needed for rs_k atomics)
        zero_k<<<(BATCH * NPTS + 255) / 256, 256, 0, stream>>>(rs, BATCH * NPTS);
        // E1: rs row-sums (no att store)
        rs_k<<<dim3(RSSPLIT, NPTS / 64, BATCH), 256, 0, stream>>>(xq, rs);
        // E2: fused QK->exp/rs->PV partials + cs partials
        attn_pv<<<dim3(1, NPTS / 64, BATCH * MSPLIT), 256, 0, stream>>>(
            xq, xv, rs, part, csp);
        // d = x - (sum partials)/(1e-9 + sum cs partials)
        diff_k<<<dim3(NPTS * 256 / 256, BATCH), 256, 0, stream>>>(
            xin, xin_bs, xin_ld, xin_po, part, csp, Dv, PO256);
        // x_out = x + relu(bn(tw@d + tb)) -> cat slice i (K=256)
        ntB(Dv, N * 256, 256, PO256, W(8 + p), 0, 256, wn[8 + p],
            cat + (size_t)i * 256, N * 1024, 1024, PO1024,
            NPTS, 256, 256, sa_tb[p], 1, sa_g[p], sa_b[p],
            xin, xin_bs, xin_ld, xin_po, 1, 0);
    }

    // ---- head ----
    nt(cat, N * 1024, 1024, PO1024, W(10), 0, 1024, wn[10],
       face, N * 512, 512, PO512, NPTS, 512, 1024,
       nullptr, 0, cf_g, cf_b, nullptr, 0, 0, 0, 2, 0);
    gmaxp_k<<<dim3(2, 16, BATCH), 256, 0, stream>>>(face, PO512, pm);
    gmaxr_k<<<dim3(BATCH * 512 / 256), 256, 0, stream>>>(pm, gm);
    bias2_k<<<dim3(2, BATCH), 256, 0, stream>>>(s1_w, gm, b2);
    nt(face, N * 512, 512, PO512, W(11), 0, 1024, wn[11],
       s1b, N * 512, 512, PO512, NPTS, 512, 512,
       b2, 2, s1_g, s1_b, nullptr, 0, 0, 0, 2, 0);
    ntB(s1b, N * 512, 512, PO512, W(12), 0, 512, wn[12],
        s2b, N * 256, 256, PO256, NPTS, 256, 512,
        nullptr, 0, s2_g, s2_b, nullptr, 0, 0, 0, 2, 0);
    ntB(s2b, N * 256, 256, PO256, W(13), 0, 256, wn[13],
        d_out, N * 50, 50, 0, NPTS, 50, 256,
        nullptr, 0, nullptr, nullptr, nullptr, 0, 0, 0, 0, 2);
}